// Round 16
// baseline (139.718 us; speedup 1.0000x reference)
//
#include <hip/hip_runtime.h>
#include <hip/hip_bf16.h>

#define LQ 2048
#define LV 2048
#define NH 256
#define NB 8

typedef __attribute__((ext_vector_type(4))) float f32x4;
typedef __attribute__((ext_vector_type(8))) short bf16x8;
typedef __attribute__((ext_vector_type(8))) _Float16 f16x8;

__device__ __forceinline__ ushort f32_bf16(float x) {
  union { float f; unsigned u; } c; c.f = x;
  unsigned r = (c.u + 0x7FFFu + ((c.u >> 16) & 1u)) >> 16;
  return (ushort)r;
}
__device__ __forceinline__ float bf16_f32(ushort h) {
  union { unsigned u; float f; } c; c.u = ((unsigned)h) << 16;
  return c.f;
}
__device__ __forceinline__ ushort f32_f16(float x) {
  union { _Float16 h; ushort u; } c; c.h = (_Float16)x; return c.u;
}
__device__ __forceinline__ float f16_f32(ushort u) {
  union { ushort u; _Float16 h; } c; c.u = u; return (float)c.h;
}
__device__ __forceinline__ void gl_lds16(const ushort* g, ushort* l) {
  __builtin_amdgcn_global_load_lds(
      (const __attribute__((address_space(1))) unsigned int*)(g),
      (__attribute__((address_space(3))) unsigned int*)(l), 16, 0, 0);
}

// ============================ NEW PATH =====================================

// ---- P0: fused prep. blocks [0,4096): Q -> Qh,Ql (f16 hi/lo);
//          blocks [4096,5120): V -> Vf (f16) + VfT (f16 transpose) ----------
__global__ __launch_bounds__(256) void k_prep2(
    const float* __restrict__ Q, const float* __restrict__ V,
    ushort* __restrict__ Qh, ushort* __restrict__ Ql,
    ushort* __restrict__ Vf, ushort* __restrict__ VfT) {
  __shared__ ushort sT[64][72];
  int bid = blockIdx.x;
  int t = threadIdx.x;
  if (bid < 4096) {
    int i = bid * 256 + t;
    float4 x = reinterpret_cast<const float4*>(Q)[i];
    ushort4 h, l;
    h.x = f32_f16(x.x); l.x = f32_f16(x.x - f16_f32(h.x));
    h.y = f32_f16(x.y); l.y = f32_f16(x.y - f16_f32(h.y));
    h.z = f32_f16(x.z); l.z = f32_f16(x.z - f16_f32(h.z));
    h.w = f32_f16(x.w); l.w = f32_f16(x.w - f16_f32(h.w));
    reinterpret_cast<ushort4*>(Qh)[i] = h;
    reinterpret_cast<ushort4*>(Ql)[i] = l;
  } else {
    int id = bid - 4096;
    int b = id & 7, vt = (id >> 3) & 31, ht = id >> 8;
    const size_t base = ((size_t)(b * LV) + vt * 64) * NH + ht * 64;
    int r0 = t >> 4, c4 = (t & 15) << 2;
    #pragma unroll
    for (int it = 0; it < 4; ++it) {
      int r = r0 + it * 16;
      size_t off = base + (size_t)r * NH + c4;
      float4 x = *reinterpret_cast<const float4*>(V + off);
      ushort4 h;
      h.x = f32_f16(x.x); h.y = f32_f16(x.y);
      h.z = f32_f16(x.z); h.w = f32_f16(x.w);
      *reinterpret_cast<ushort4*>(Vf + off) = h;
      *reinterpret_cast<ushort4*>(&sT[r][c4]) = h;
    }
    __syncthreads();
    int hh = t & 63, vc = t >> 6;
    ushort tmp[16];
    #pragma unroll
    for (int j = 0; j < 16; ++j) tmp[j] = sT[vc * 16 + j][hh];
    ushort* dst = VfT + ((size_t)(b * NH) + ht * 64 + hh) * LV + vt * 64 + vc * 16;
    *reinterpret_cast<ushort4*>(dst)      = *reinterpret_cast<ushort4*>(&tmp[0]);
    *reinterpret_cast<ushort4*>(dst + 4)  = *reinterpret_cast<ushort4*>(&tmp[4]);
    *reinterpret_cast<ushort4*>(dst + 8)  = *reinterpret_cast<ushort4*>(&tmp[8]);
    *reinterpret_cast<ushort4*>(dst + 12) = *reinterpret_cast<ushort4*>(&tmp[12]);
  }
}

// ---- K1: S = Q*V^T, f16 one-sided split (2 MFMA), 128x256 tile, 64KB LDS --
// 2 blocks/CU (was 1): inter-block overlap covers the 2-barrier drain.
// grid 1024 = 8 b * 16 qt * 8 vt; 8 waves: 4 wq (32 rows) x 2 wv (128 cols).
__global__ __launch_bounds__(512) void k_scores10(
    const ushort* __restrict__ Qh, const ushort* __restrict__ Ql,
    const ushort* __restrict__ Vf,
    float* __restrict__ S, float2* __restrict__ PS) {
  extern __shared__ ushort dynlds[];  // staging 64KB; epilogue repack 68KB
  int id = blockIdx.x;
  int b = id & 7, qt = (id >> 3) & 15, vt = id >> 7;
  int t = threadIdx.x, lane = t & 63, w = t >> 6;

  const size_t bq = (size_t)(b * LQ) + qt * 128;
  const size_t bv = (size_t)(b * LV) + vt * 256;

  // staging layout per buf (32KB): Qh[128][32] | Ql[128][32] | Vf[256][32]
#define LBASE(buf, arr) \
  ((char*)dynlds + (buf) * 32768 + ((arr) < 2 ? (arr) * 8192 : 16384))

  // 4 x gl_lds16/thread: Qh,Ql row t>>2 (128 rows) + Vf rows t>>2, 128+(t>>2)
#define STAGE(buf, kt)                                                      \
  {                                                                         \
    int krow = t >> 2, c = t & 3;                                           \
    int csrc = c ^ ((krow >> 1) & 3);                                       \
    size_t gq = (bq + krow) * NH + (kt) * 32 + csrc * 8;                    \
    gl_lds16(Qh + gq, (ushort*)(LBASE(buf, 0) + krow * 64 + c * 16));       \
    gl_lds16(Ql + gq, (ushort*)(LBASE(buf, 1) + krow * 64 + c * 16));       \
    _Pragma("unroll")                                                       \
    for (int hh = 0; hh < 2; ++hh) {                                        \
      int row = hh * 128 + krow;                                            \
      int csv = c ^ ((row >> 1) & 3);                                       \
      size_t gv = (bv + row) * NH + (kt) * 32 + csv * 8;                    \
      gl_lds16(Vf + gv, (ushort*)(LBASE(buf, 2) + row * 64 + c * 16));      \
    }                                                                       \
  }

  int wq = w >> 1, wv = w & 1;           // 4x2 wave grid; 32q x 128v / wave
  int ar = wq * 32 + (lane & 15);
  int br = wv * 128 + (lane & 15);
  int kb = lane >> 4;

  f32x4 acc[2][8] = {};

  STAGE(0, 0);
  STAGE(1, 1);

  #pragma unroll
  for (int kt = 0; kt < 8; ++kt) {
    const int cur = kt & 1;
    if (kt < 7) { asm volatile("s_waitcnt vmcnt(4)" ::: "memory"); }
    else        { asm volatile("s_waitcnt vmcnt(0)" ::: "memory"); }
    __builtin_amdgcn_sched_barrier(0);
    __builtin_amdgcn_s_barrier();
    __builtin_amdgcn_sched_barrier(0);

    f16x8 ah[2], al[2];
    #pragma unroll
    for (int m = 0; m < 2; ++m) {
      int r = ar + m * 16;
      int off = r * 64 + ((kb ^ ((r >> 1) & 3)) << 4);
      ah[m] = *reinterpret_cast<const f16x8*>(LBASE(cur, 0) + off);
      al[m] = *reinterpret_cast<const f16x8*>(LBASE(cur, 1) + off);
    }
    __builtin_amdgcn_s_setprio(1);
    #pragma unroll
    for (int n = 0; n < 8; ++n) {
      int r = br + n * 16;
      int off = r * 64 + ((kb ^ ((r >> 1) & 3)) << 4);
      f16x8 bf = *reinterpret_cast<const f16x8*>(LBASE(cur, 2) + off);
      #pragma unroll
      for (int m = 0; m < 2; ++m) {
        acc[m][n] = __builtin_amdgcn_mfma_f32_16x16x32_f16(ah[m], bf, acc[m][n], 0, 0, 0);
        acc[m][n] = __builtin_amdgcn_mfma_f32_16x16x32_f16(al[m], bf, acc[m][n], 0, 0, 0);
      }
    }
    __builtin_amdgcn_s_setprio(0);
    __builtin_amdgcn_sched_barrier(0);
    __builtin_amdgcn_s_barrier();
    __builtin_amdgcn_sched_barrier(0);
    if (kt < 6) STAGE(cur, kt + 2);
  }

  // ---- epilogue: partials + COALESCED f16 exp store via per-wave LDS ----
  // (all staging reads complete at last barrier -> safe to reuse dynlds)
  const int g = lane >> 4, c0 = lane & 15;
  #pragma unroll
  for (int m = 0; m < 2; ++m) {
    ushort* lw = dynlds + (w * 2 + m) * (16 * 136);  // disjoint regions
    #pragma unroll
    for (int j = 0; j < 4; ++j) {
      float mx = acc[m][0][j];
      #pragma unroll
      for (int n = 1; n < 8; ++n) mx = fmaxf(mx, acc[m][n][j]);
      #pragma unroll
      for (int off = 1; off < 16; off <<= 1) mx = fmaxf(mx, __shfl_xor(mx, off));
      float e[8];
      float s = 0.f;
      #pragma unroll
      for (int n = 0; n < 8; ++n) { e[n] = __expf(acc[m][n][j] - mx); s += e[n]; }
      #pragma unroll
      for (int off = 1; off < 16; off <<= 1) s += __shfl_xor(s, off);
      if (c0 == 0) {
        int row = qt * 128 + wq * 32 + m * 16 + g * 4 + j;
        float2 v; v.x = mx; v.y = s;
        PS[((size_t)(b * LQ) + row) * 16 + vt * 2 + wv] = v;
      }
      int r16 = g * 4 + j;
      #pragma unroll
      for (int n = 0; n < 8; ++n) lw[r16 * 136 + c0 + n * 16] = f32_f16(e[n]);
    }
    int row0 = qt * 128 + wq * 32 + m * 16;
    int cb = vt * 256 + wv * 128;
    #pragma unroll
    for (int k2 = 0; k2 < 4; ++k2) {
      int chunk = k2 * 64 + lane;         // 0..255
      int rr = chunk >> 4, pos = chunk & 15;
      f16x8 vdat = *reinterpret_cast<const f16x8*>(&lw[rr * 136 + pos * 8]);
      ushort* pr = (ushort*)(S + ((size_t)(b * LQ) + row0 + rr) * LV + 1024);
      *reinterpret_cast<f16x8*>(&pr[cb + pos * 8]) = vdat;
    }
  }
#undef STAGE
#undef LBASE
}

// ---- K2: factors from partials + attn=f16P*factor (f32 write) + P*V (f16) -
// (proven R14 kernel, unchanged: LDS-only loop barrier, no vmcnt drain)
__global__ __launch_bounds__(512) void k_ctx12(
    const ushort* __restrict__ VfT, const float2* __restrict__ PS,
    float* __restrict__ A, float* __restrict__ C) {
  int id = blockIdx.x;
  int b = id & 7, qs = id >> 3;
  __shared__ float lf[32][16];                      // per (row, 128-tile) factor
  __shared__ __align__(16) ushort sP[4][32 * 64];   // swizzled [q][v] f16, 4x4KB

  int t = threadIdx.x, lane = t & 63, w = t >> 6;
  float* Ab = A + (size_t)b * LQ * LV + (size_t)qs * 32 * LV;
  const ushort* Vb = VfT + (size_t)b * NH * LV;

  const int prow = t >> 4, pc = (t & 15) << 2;   // 4 cols per thread per chunk
  float* aaddr = Ab + (size_t)prow * LV + pc;
  const ushort* a16 = (const ushort*)(Ab + (size_t)prow * LV + 1024) + pc;
  const int poff = (prow * 128 + pc * 2) ^ ((prow & 7) << 4);

  // stats: 16 threads/row; combine 16 partials -> global (M, Z); store factor
  {
    int row = t >> 4, seg = t & 15;
    float2 p = PS[((size_t)(b * LQ) + qs * 32 + row) * 16 + seg];
    float M = p.x, s = p.y;
    #pragma unroll
    for (int off = 1; off < 16; off <<= 1) {
      float mo = __shfl_xor(M, off), so = __shfl_xor(s, off);
      float mn = fmaxf(M, mo);
      s = s * __expf(M - mn) + so * __expf(mo - mn);
      M = mn;
    }
    lf[row][seg] = __expf(p.x - M) / s;
  }
  __syncthreads();

#define PRODUCE(xv, v0, buf, fac)                                           \
  {                                                                         \
    float4 p;                                                               \
    p.x = f16_f32((xv).x) * (fac); p.y = f16_f32((xv).y) * (fac);           \
    p.z = f16_f32((xv).z) * (fac); p.w = f16_f32((xv).w) * (fac);           \
    *reinterpret_cast<float4*>(aaddr + (v0)) = p;                           \
    ushort4 pk;                                                             \
    pk.x = f32_f16(p.x); pk.y = f32_f16(p.y);                               \
    pk.z = f32_f16(p.z); pk.w = f32_f16(p.w);                               \
    *reinterpret_cast<ushort4*>((char*)&sP[buf][0] + poff) = pk;            \
  }

  // prologue: chunks 0,1 (tile 0) -> sP[0],sP[1]; prefetch chunks 2,3
  ushort4 x0 = *reinterpret_cast<const ushort4*>(a16);
  ushort4 x1 = *reinterpret_cast<const ushort4*>(a16 + 64);
  {
    float f0 = lf[prow][0];
    PRODUCE(x0, 0, 0, f0);
    PRODUCE(x1, 64, 1, f0);
  }
  x0 = *reinterpret_cast<const ushort4*>(a16 + 128);
  x1 = *reinterpret_cast<const ushort4*>(a16 + 192);
  __syncthreads();

  f32x4 acc[2][2] = {};
  const int NP = LV / 128;  // 16 pairs (tile p = pair p)

  for (int p = 0; p < NP; ++p) {
    const int cur = (p & 1) << 1;
    const int nxt = cur ^ 2;
    const int v0 = p * 128;
    if (p + 1 < NP) {
      float fn = lf[prow][p + 1];
      PRODUCE(x0, v0 + 128, nxt, fn);
      PRODUCE(x1, v0 + 192, nxt + 1, fn);
    }
    if (p + 2 < NP) {
      x0 = *reinterpret_cast<const ushort4*>(a16 + v0 + 256);
      x1 = *reinterpret_cast<const ushort4*>(a16 + v0 + 320);
    }

    #pragma unroll
    for (int c = 0; c < 2; ++c) {
      #pragma unroll
      for (int ks = 0; ks < 2; ++ks) {
        int vbyte = ks * 64 + ((lane >> 4) << 4);
        f16x8 pa[2];
        #pragma unroll
        for (int i2 = 0; i2 < 2; ++i2) {
          int arow = i2 * 16 + (lane & 15);
          pa[i2] = *reinterpret_cast<const f16x8*>(
              (char*)&sP[cur + c][0] + ((arow * 128 + vbyte) ^ ((arow & 7) << 4)));
        }
        #pragma unroll
        for (int n = 0; n < 2; ++n) {
          int hrow = w * 32 + n * 16 + (lane & 15);
          f16x8 vb = *reinterpret_cast<const f16x8*>(
              Vb + (size_t)hrow * LV + v0 + c * 64 + ks * 32 + ((lane >> 4) << 3));
          #pragma unroll
          for (int i2 = 0; i2 < 2; ++i2)
            acc[i2][n] = __builtin_amdgcn_mfma_f32_16x16x32_f16(pa[i2], vb, acc[i2][n], 0, 0, 0);
        }
      }
    }
    asm volatile("s_waitcnt lgkmcnt(0)" ::: "memory");
    __builtin_amdgcn_s_barrier();
  }
#undef PRODUCE

  float* Cb = C + ((size_t)b * LQ + qs * 32) * NH + w * 32;
  int rb = (lane >> 4) << 2, c0 = lane & 15;
  #pragma unroll
  for (int i2 = 0; i2 < 2; ++i2)
    #pragma unroll
    for (int j = 0; j < 4; ++j)
      #pragma unroll
      for (int n = 0; n < 2; ++n)
        Cb[(size_t)(i2 * 16 + rb + j) * NH + n * 16 + c0] = acc[i2][n][j];
}

// ============================ FALLBACK PATH (round-0) ======================

__global__ __launch_bounds__(256) void k_scores_fb(
    const float* __restrict__ Q, const float* __restrict__ V,
    float* __restrict__ S) {
  int id = blockIdx.x;
  int b = id & 7;
  int inner = id >> 3;
  int qt = inner & 31;
  int vt = inner >> 5;
  __shared__ ushort sQh[64 * 64], sQl[64 * 64], sVh[64 * 64], sVl[64 * 64];
  const float* Qb = Q + (size_t)(b * LQ + qt * 64) * NH;
  const float* Vb = V + (size_t)(b * LV + vt * 64) * NH;
  const int t = threadIdx.x;
  const int lane = t & 63;
  const int w = t >> 6;
  f32x4 acc[4] = {};
  const int row0 = t >> 4;
  const int col4 = (t & 15) << 2;
  for (int kc = 0; kc < 4; ++kc) {
    #pragma unroll
    for (int it = 0; it < 4; ++it) {
      int row = row0 + (it << 4);
      const float4 qx = *reinterpret_cast<const float4*>(Qb + (size_t)row * NH + kc * 64 + col4);
      const float4 vx = *reinterpret_cast<const float4*>(Vb + (size_t)row * NH + kc * 64 + col4);
      int off = ((row * 128 + col4 * 2) ^ ((row & 7) << 4)) >> 1;
      ushort4 h, l;
      h.x = f32_bf16(qx.x); l.x = f32_bf16(qx.x - bf16_f32(h.x));
      h.y = f32_bf16(qx.y); l.y = f32_bf16(qx.y - bf16_f32(h.y));
      h.z = f32_bf16(qx.z); l.z = f32_bf16(qx.z - bf16_f32(h.z));
      h.w = f32_bf16(qx.w); l.w = f32_bf16(qx.w - bf16_f32(h.w));
      *reinterpret_cast<ushort4*>(&sQh[off]) = h;
      *reinterpret_cast<ushort4*>(&sQl[off]) = l;
      h.x = f32_bf16(vx.x); l.x = f32_bf16(vx.x - bf16_f32(h.x));
      h.y = f32_bf16(vx.y); l.y = f32_bf16(vx.y - bf16_f32(h.y));
      h.z = f32_bf16(vx.z); l.z = f32_bf16(vx.z - bf16_f32(h.z));
      h.w = f32_bf16(vx.w); l.w = f32_bf16(vx.w - bf16_f32(h.w));
      *reinterpret_cast<ushort4*>(&sVh[off]) = h;
      *reinterpret_cast<ushort4*>(&sVl[off]) = l;
    }
    __syncthreads();
    int arow = (w << 4) + (lane & 15);
    int abase = arow * 128;
    int aswz = (arow & 7) << 4;
    #pragma unroll
    for (int ks = 0; ks < 2; ++ks) {
      int koffB = (ks << 6) + ((lane >> 4) << 4);
      int aoff = ((abase + koffB) ^ aswz) >> 1;
      bf16x8 ah = *reinterpret_cast<const bf16x8*>(&sQh[aoff]);
      bf16x8 al = *reinterpret_cast<const bf16x8*>(&sQl[aoff]);
      #pragma unroll
      for (int n = 0; n < 4; ++n) {
        int brow = (n << 4) + (lane & 15);
        int boff = (((brow * 128) + koffB) ^ ((brow & 7) << 4)) >> 1;
        bf16x8 bh = *reinterpret_cast<const bf16x8*>(&sVh[boff]);
        bf16x8 bl = *reinterpret_cast<const bf16x8*>(&sVl[boff]);
        acc[n] = __builtin_amdgcn_mfma_f32_16x16x32_bf16(ah, bh, acc[n], 0, 0, 0);
        acc[n] = __builtin_amdgcn_mfma_f32_16x16x32_bf16(ah, bl, acc[n], 0, 0, 0);
        acc[n] = __builtin_amdgcn_mfma_f32_16x16x32_bf16(al, bh, acc[n], 0, 0, 0);
      }
    }
    __syncthreads();
  }
  float* Sp = S + (size_t)b * LQ * LV + (size_t)(qt * 64) * LV + vt * 64;
  int rbase = (w << 4) + ((lane >> 4) << 2);
  int c0 = lane & 15;
  #pragma unroll
  for (int n = 0; n < 4; ++n)
    #pragma unroll
    for (int j = 0; j < 4; ++j)
      Sp[(size_t)(rbase + j) * LV + (n << 4) + c0] = acc[n][j];
}

__global__ __launch_bounds__(256) void k_stats_fb(const float* __restrict__ S,
                                                  float* __restrict__ ml) {
  const size_t r = blockIdx.x;
  const float* row = S + r * LV;
  int t = threadIdx.x;
  float4 a = *reinterpret_cast<const float4*>(row + (t << 2));
  float4 c = *reinterpret_cast<const float4*>(row + 1024 + (t << 2));
  float m = fmaxf(fmaxf(fmaxf(a.x, a.y), fmaxf(a.z, a.w)),
                  fmaxf(fmaxf(c.x, c.y), fmaxf(c.z, c.w)));
  #pragma unroll
  for (int off = 32; off; off >>= 1) m = fmaxf(m, __shfl_xor(m, off));
  __shared__ float redm[4];
  __shared__ float reds[4];
  if ((t & 63) == 0) redm[t >> 6] = m;
  __syncthreads();
  m = fmaxf(fmaxf(redm[0], redm[1]), fmaxf(redm[2], redm[3]));
  float s = __expf(a.x - m) + __expf(a.y - m) + __expf(a.z - m) + __expf(a.w - m)
          + __expf(c.x - m) + __expf(c.y - m) + __expf(c.z - m) + __expf(c.w - m);
  #pragma unroll
  for (int off = 32; off; off >>= 1) s += __shfl_xor(s, off);
  if ((t & 63) == 0) reds[t >> 6] = s;
  __syncthreads();
  if (t == 0) {
    float tot = reds[0] + reds[1] + reds[2] + reds[3];
    ml[2 * r] = m;
    ml[2 * r + 1] = 1.0f / tot;
  }
}

__global__ __launch_bounds__(256) void k_ctx_fb(
    const float* __restrict__ V, const float* __restrict__ ml,
    float* __restrict__ A, float* __restrict__ C) {
  int id = blockIdx.x;
  int b = id & 7;
  int qt = id >> 3;
  __shared__ ushort sP[32 * 40];
  __shared__ ushort sVT[256 * 40];
  __shared__ float lmv[32], liv[32];
  int t = threadIdx.x;
  int lane = t & 63;
  int w = t >> 6;
  int wr = w >> 1, wh = w & 1;
  if (t < 32) {
    size_t r = (size_t)b * LQ + qt * 32 + t;
    lmv[t] = ml[2 * r];
    liv[t] = ml[2 * r + 1];
  }
  __syncthreads();
  f32x4 acc[8] = {};
  float* Ab = A + (size_t)b * LQ * LV + (size_t)(qt * 32) * LV;
  const float* Vb = V + (size_t)b * LV * NH;
  const int prow = t >> 3;
  const int pv4 = (t & 7) << 2;
  for (int v0 = 0; v0 < LV; v0 += 32) {
    {
      float* addr = Ab + (size_t)prow * LV + v0 + pv4;
      float4 s4 = *reinterpret_cast<const float4*>(addr);
      float m = lmv[prow], inv = liv[prow];
      float4 p4;
      p4.x = __expf(s4.x - m) * inv;
      p4.y = __expf(s4.y - m) * inv;
      p4.z = __expf(s4.z - m) * inv;
      p4.w = __expf(s4.w - m) * inv;
      *reinterpret_cast<float4*>(addr) = p4;
      ushort4 pb;
      pb.x = f32_bf16(p4.x); pb.y = f32_bf16(p4.y);
      pb.z = f32_bf16(p4.z); pb.w = f32_bf16(p4.w);
      *reinterpret_cast<ushort4*>(&sP[prow * 40 + pv4]) = pb;
    }
    #pragma unroll 4
    for (int vl = 0; vl < 32; ++vl) {
      float x = Vb[(size_t)(v0 + vl) * NH + t];
      sVT[t * 40 + vl] = f32_bf16(x);
    }
    __syncthreads();
    bf16x8 pa = *reinterpret_cast<const bf16x8*>(
        &sP[((wr << 4) + (lane & 15)) * 40 + ((lane >> 4) << 3)]);
    #pragma unroll
    for (int n = 0; n < 8; ++n) {
      int hrow = (wh << 7) + (n << 4) + (lane & 15);
      bf16x8 vb = *reinterpret_cast<const bf16x8*>(
          &sVT[hrow * 40 + ((lane >> 4) << 3)]);
      acc[n] = __builtin_amdgcn_mfma_f32_16x16x32_bf16(pa, vb, acc[n], 0, 0, 0);
    }
    __syncthreads();
  }
  float* Cb = C + ((size_t)b * LQ + qt * 32) * NH;
  int rbase = (wr << 4) + ((lane >> 4) << 2);
  int c0 = lane & 15;
  #pragma unroll
  for (int n = 0; n < 8; ++n)
    #pragma unroll
    for (int j = 0; j < 4; ++j)
      Cb[(size_t)(rbase + j) * NH + (wh << 7) + (n << 4) + c0] = acc[n][j];
}

// ===========================================================================

extern "C" void kernel_launch(void* const* d_in, const int* in_sizes, int n_in,
                              void* d_out, int out_size, void* d_ws, size_t ws_size,
                              hipStream_t stream) {
  const float* Q = (const float*)d_in[0];
  const float* V = (const float*)d_in[1];
  float* out = (float*)d_out;
  float* C = out;                                  // context: 8*2048*256
  float* A = out + (size_t)NB * LQ * NH;           // attn:    8*2048*2048

  const size_t NE = (size_t)NB * LQ * NH;          // 4,194,304 elems
  const size_t PSN = (size_t)NB * LQ * 16;         // 262,144 float2
  const size_t need = NE * 2 * 4 + PSN * 8;        // ≈ 34 MiB
  const int DYN_LDS = 16 * 16 * 136 * 2;           // 69632 B (>= 64KB staging)

  bool big_lds_ok =
      hipFuncSetAttribute((const void*)k_scores10,
                          hipFuncAttributeMaxDynamicSharedMemorySize,
                          DYN_LDS) == hipSuccess;

  if (ws_size >= need && big_lds_ok) {
    ushort* Qh  = (ushort*)d_ws;
    ushort* Ql  = Qh + NE;
    ushort* Vf  = Ql + NE;
    ushort* VfT = Vf + NE;
    float2* PS  = (float2*)(VfT + NE);
    k_prep2<<<dim3(4096 + NB * 32 * 4), dim3(256), 0, stream>>>(Q, V, Qh, Ql, Vf, VfT);
    k_scores10<<<dim3(NB * 16 * 8), dim3(512), DYN_LDS, stream>>>(Qh, Ql, Vf, A, PS);
    k_ctx12<<<dim3(NB * 64), dim3(512), 0, stream>>>(VfT, PS, A, C);
  } else {
    float* ml = (float*)d_ws;                      // 128 KB fallback scratch
    k_scores_fb<<<dim3(NB * 32 * 32), dim3(256), 0, stream>>>(Q, V, A);
    k_stats_fb<<<dim3(NB * LQ), dim3(256), 0, stream>>>(A, ml);
    k_ctx_fb<<<dim3(NB * 64), dim3(256), 0, stream>>>(V, ml, A, C);
  }
}

// Round 17
// 132.799 us; speedup vs baseline: 1.0521x; 1.0521x over previous
//
#include <hip/hip_runtime.h>
#include <hip/hip_bf16.h>

#define LQ 2048
#define LV 2048
#define NH 256
#define NB 8

typedef __attribute__((ext_vector_type(4))) float f32x4;
typedef __attribute__((ext_vector_type(8))) short bf16x8;
typedef __attribute__((ext_vector_type(8))) _Float16 f16x8;

__device__ __forceinline__ ushort f32_bf16(float x) {
  union { float f; unsigned u; } c; c.f = x;
  unsigned r = (c.u + 0x7FFFu + ((c.u >> 16) & 1u)) >> 16;
  return (ushort)r;
}
__device__ __forceinline__ float bf16_f32(ushort h) {
  union { unsigned u; float f; } c; c.u = ((unsigned)h) << 16;
  return c.f;
}
__device__ __forceinline__ ushort f32_f16(float x) {
  union { _Float16 h; ushort u; } c; c.h = (_Float16)x; return c.u;
}
__device__ __forceinline__ float f16_f32(ushort u) {
  union { ushort u; _Float16 h; } c; c.u = u; return (float)c.h;
}
__device__ __forceinline__ void gl_lds16(const ushort* g, ushort* l) {
  __builtin_amdgcn_global_load_lds(
      (const __attribute__((address_space(1))) unsigned int*)(g),
      (__attribute__((address_space(3))) unsigned int*)(l), 16, 0, 0);
}

// ============================ NEW PATH =====================================

// ---- P0: fused prep. blocks [0,4096): Q -> Qh,Ql (f16 hi/lo);
//          blocks [4096,5120): V -> Vf (f16) + VfT (f16 transpose) ----------
__global__ __launch_bounds__(256) void k_prep2(
    const float* __restrict__ Q, const float* __restrict__ V,
    ushort* __restrict__ Qh, ushort* __restrict__ Ql,
    ushort* __restrict__ Vf, ushort* __restrict__ VfT) {
  __shared__ ushort sT[64][72];
  int bid = blockIdx.x;
  int t = threadIdx.x;
  if (bid < 4096) {
    int i = bid * 256 + t;
    float4 x = reinterpret_cast<const float4*>(Q)[i];
    ushort4 h, l;
    h.x = f32_f16(x.x); l.x = f32_f16(x.x - f16_f32(h.x));
    h.y = f32_f16(x.y); l.y = f32_f16(x.y - f16_f32(h.y));
    h.z = f32_f16(x.z); l.z = f32_f16(x.z - f16_f32(h.z));
    h.w = f32_f16(x.w); l.w = f32_f16(x.w - f16_f32(h.w));
    reinterpret_cast<ushort4*>(Qh)[i] = h;
    reinterpret_cast<ushort4*>(Ql)[i] = l;
  } else {
    int id = bid - 4096;
    int b = id & 7, vt = (id >> 3) & 31, ht = id >> 8;
    const size_t base = ((size_t)(b * LV) + vt * 64) * NH + ht * 64;
    int r0 = t >> 4, c4 = (t & 15) << 2;
    #pragma unroll
    for (int it = 0; it < 4; ++it) {
      int r = r0 + it * 16;
      size_t off = base + (size_t)r * NH + c4;
      float4 x = *reinterpret_cast<const float4*>(V + off);
      ushort4 h;
      h.x = f32_f16(x.x); h.y = f32_f16(x.y);
      h.z = f32_f16(x.z); h.w = f32_f16(x.w);
      *reinterpret_cast<ushort4*>(Vf + off) = h;
      *reinterpret_cast<ushort4*>(&sT[r][c4]) = h;
    }
    __syncthreads();
    int hh = t & 63, vc = t >> 6;
    ushort tmp[16];
    #pragma unroll
    for (int j = 0; j < 16; ++j) tmp[j] = sT[vc * 16 + j][hh];
    ushort* dst = VfT + ((size_t)(b * NH) + ht * 64 + hh) * LV + vt * 64 + vc * 16;
    *reinterpret_cast<ushort4*>(dst)      = *reinterpret_cast<ushort4*>(&tmp[0]);
    *reinterpret_cast<ushort4*>(dst + 4)  = *reinterpret_cast<ushort4*>(&tmp[4]);
    *reinterpret_cast<ushort4*>(dst + 8)  = *reinterpret_cast<ushort4*>(&tmp[8]);
    *reinterpret_cast<ushort4*>(dst + 12) = *reinterpret_cast<ushort4*>(&tmp[12]);
  }
}

// ---- K1: S = Q*V^T, f16 one-sided split (2 MFMA), 256x256 block, 96KB LDS -
// (proven R13/R14 kernel, unchanged)
__global__ __launch_bounds__(512) void k_scores9(
    const ushort* __restrict__ Qh, const ushort* __restrict__ Ql,
    const ushort* __restrict__ Vf,
    float* __restrict__ S, float2* __restrict__ PS) {
  extern __shared__ ushort dynlds[];  // [buf2][arr3][row256][col32] = 96KB
  int id = blockIdx.x;
  int b = id & 7, qt = (id >> 3) & 7, vt = id >> 6;
  int t = threadIdx.x, lane = t & 63, w = t >> 6;

  const size_t bq = (size_t)(b * LQ) + qt * 256;
  const size_t bv = (size_t)(b * LV) + vt * 256;

#define LBASE(buf, arr) ((char*)dynlds + ((buf) * 3 + (arr)) * (256 * 64))

#define STAGE(buf, kt)                                                      \
  {                                                                         \
    int krow = t >> 2, c = t & 3;                                           \
    _Pragma("unroll")                                                       \
    for (int hh = 0; hh < 2; ++hh) {                                        \
      int row = hh * 128 + krow;                                            \
      int csrc = c ^ ((row >> 1) & 3);                                      \
      size_t gq = (bq + row) * NH + (kt) * 32 + csrc * 8;                   \
      size_t gv = (bv + row) * NH + (kt) * 32 + csrc * 8;                   \
      gl_lds16(Qh + gq, (ushort*)(LBASE(buf, 0) + row * 64 + c * 16));      \
      gl_lds16(Ql + gq, (ushort*)(LBASE(buf, 1) + row * 64 + c * 16));      \
      gl_lds16(Vf + gv, (ushort*)(LBASE(buf, 2) + row * 64 + c * 16));      \
    }                                                                       \
  }

  int wq = w >> 1, wv = w & 1;           // 4x2 wave grid; 64q x 128v / wave
  int ar = wq * 64 + (lane & 15);
  int br = wv * 128 + (lane & 15);
  int kb = lane >> 4;

  f32x4 acc[4][8] = {};

  STAGE(0, 0);
  STAGE(1, 1);

  #pragma unroll
  for (int kt = 0; kt < 8; ++kt) {
    const int cur = kt & 1;
    if (kt < 7) { asm volatile("s_waitcnt vmcnt(6)" ::: "memory"); }
    else        { asm volatile("s_waitcnt vmcnt(0)" ::: "memory"); }
    __builtin_amdgcn_sched_barrier(0);
    __builtin_amdgcn_s_barrier();
    __builtin_amdgcn_sched_barrier(0);

    f16x8 ah[4], al[4];
    #pragma unroll
    for (int m = 0; m < 4; ++m) {
      int r = ar + m * 16;
      int off = r * 64 + ((kb ^ ((r >> 1) & 3)) << 4);
      ah[m] = *reinterpret_cast<const f16x8*>(LBASE(cur, 0) + off);
      al[m] = *reinterpret_cast<const f16x8*>(LBASE(cur, 1) + off);
    }
    __builtin_amdgcn_s_setprio(1);
    #pragma unroll
    for (int n = 0; n < 8; ++n) {
      int r = br + n * 16;
      int off = r * 64 + ((kb ^ ((r >> 1) & 3)) << 4);
      f16x8 bf = *reinterpret_cast<const f16x8*>(LBASE(cur, 2) + off);
      #pragma unroll
      for (int m = 0; m < 4; ++m) {
        acc[m][n] = __builtin_amdgcn_mfma_f32_16x16x32_f16(ah[m], bf, acc[m][n], 0, 0, 0);
        acc[m][n] = __builtin_amdgcn_mfma_f32_16x16x32_f16(al[m], bf, acc[m][n], 0, 0, 0);
      }
    }
    __builtin_amdgcn_s_setprio(0);
    __builtin_amdgcn_sched_barrier(0);
    __builtin_amdgcn_s_barrier();
    __builtin_amdgcn_sched_barrier(0);
    if (kt < 6) STAGE(cur, kt + 2);
  }

  // ---- epilogue: partials + COALESCED f16 exp store via per-wave LDS ----
  const int g = lane >> 4, c0 = lane & 15;
  #pragma unroll
  for (int m = 0; m < 4; ++m) {
    ushort* lw = dynlds + (w * 2 + (m & 1)) * (16 * 136);
    #pragma unroll
    for (int j = 0; j < 4; ++j) {
      float mx = acc[m][0][j];
      #pragma unroll
      for (int n = 1; n < 8; ++n) mx = fmaxf(mx, acc[m][n][j]);
      #pragma unroll
      for (int off = 1; off < 16; off <<= 1) mx = fmaxf(mx, __shfl_xor(mx, off));
      float e[8];
      float s = 0.f;
      #pragma unroll
      for (int n = 0; n < 8; ++n) { e[n] = __expf(acc[m][n][j] - mx); s += e[n]; }
      #pragma unroll
      for (int off = 1; off < 16; off <<= 1) s += __shfl_xor(s, off);
      if (c0 == 0) {
        int row = qt * 256 + wq * 64 + m * 16 + g * 4 + j;
        float2 v; v.x = mx; v.y = s;
        PS[((size_t)(b * LQ) + row) * 16 + vt * 2 + wv] = v;
      }
      int r16 = g * 4 + j;
      #pragma unroll
      for (int n = 0; n < 8; ++n) lw[r16 * 136 + c0 + n * 16] = f32_f16(e[n]);
    }
    int row0 = qt * 256 + wq * 64 + m * 16;
    int cb = vt * 256 + wv * 128;
    #pragma unroll
    for (int k2 = 0; k2 < 4; ++k2) {
      int chunk = k2 * 64 + lane;         // 0..255
      int rr = chunk >> 4, pos = chunk & 15;
      f16x8 vdat = *reinterpret_cast<const f16x8*>(&lw[rr * 136 + pos * 8]);
      ushort* pr = (ushort*)(S + ((size_t)(b * LQ) + row0 + rr) * LV + 1024);
      *reinterpret_cast<f16x8*>(&pr[cb + pos * 8]) = vdat;
    }
  }
#undef STAGE
#undef LBASE
}

// ---- K2: factors from partials + attn=f16P*factor (f32 write) + P*V (f16) -
// (proven R14 kernel: LDS-only loop barrier, no vmcnt drain)
__global__ __launch_bounds__(512) void k_ctx12(
    const ushort* __restrict__ VfT, const float2* __restrict__ PS,
    float* __restrict__ A, float* __restrict__ C) {
  int id = blockIdx.x;
  int b = id & 7, qs = id >> 3;
  __shared__ float lf[32][16];                      // per (row, 128-tile) factor
  __shared__ __align__(16) ushort sP[4][32 * 64];   // swizzled [q][v] f16, 4x4KB

  int t = threadIdx.x, lane = t & 63, w = t >> 6;
  float* Ab = A + (size_t)b * LQ * LV + (size_t)qs * 32 * LV;
  const ushort* Vb = VfT + (size_t)b * NH * LV;

  const int prow = t >> 4, pc = (t & 15) << 2;   // 4 cols per thread per chunk
  float* aaddr = Ab + (size_t)prow * LV + pc;
  const ushort* a16 = (const ushort*)(Ab + (size_t)prow * LV + 1024) + pc;
  const int poff = (prow * 128 + pc * 2) ^ ((prow & 7) << 4);

  // stats: 16 threads/row; combine 16 partials -> global (M, Z); store factor
  {
    int row = t >> 4, seg = t & 15;
    float2 p = PS[((size_t)(b * LQ) + qs * 32 + row) * 16 + seg];
    float M = p.x, s = p.y;
    #pragma unroll
    for (int off = 1; off < 16; off <<= 1) {
      float mo = __shfl_xor(M, off), so = __shfl_xor(s, off);
      float mn = fmaxf(M, mo);
      s = s * __expf(M - mn) + so * __expf(mo - mn);
      M = mn;
    }
    lf[row][seg] = __expf(p.x - M) / s;
  }
  __syncthreads();

#define PRODUCE(xv, v0, buf, fac)                                           \
  {                                                                         \
    float4 p;                                                               \
    p.x = f16_f32((xv).x) * (fac); p.y = f16_f32((xv).y) * (fac);           \
    p.z = f16_f32((xv).z) * (fac); p.w = f16_f32((xv).w) * (fac);           \
    *reinterpret_cast<float4*>(aaddr + (v0)) = p;                           \
    ushort4 pk;                                                             \
    pk.x = f32_f16(p.x); pk.y = f32_f16(p.y);                               \
    pk.z = f32_f16(p.z); pk.w = f32_f16(p.w);                               \
    *reinterpret_cast<ushort4*>((char*)&sP[buf][0] + poff) = pk;            \
  }

  // prologue: chunks 0,1 (tile 0) -> sP[0],sP[1]; prefetch chunks 2,3
  ushort4 x0 = *reinterpret_cast<const ushort4*>(a16);
  ushort4 x1 = *reinterpret_cast<const ushort4*>(a16 + 64);
  {
    float f0 = lf[prow][0];
    PRODUCE(x0, 0, 0, f0);
    PRODUCE(x1, 64, 1, f0);
  }
  x0 = *reinterpret_cast<const ushort4*>(a16 + 128);
  x1 = *reinterpret_cast<const ushort4*>(a16 + 192);
  __syncthreads();

  f32x4 acc[2][2] = {};
  const int NP = LV / 128;  // 16 pairs (tile p = pair p)

  for (int p = 0; p < NP; ++p) {
    const int cur = (p & 1) << 1;
    const int nxt = cur ^ 2;
    const int v0 = p * 128;
    if (p + 1 < NP) {
      float fn = lf[prow][p + 1];
      PRODUCE(x0, v0 + 128, nxt, fn);
      PRODUCE(x1, v0 + 192, nxt + 1, fn);
    }
    if (p + 2 < NP) {
      x0 = *reinterpret_cast<const ushort4*>(a16 + v0 + 256);
      x1 = *reinterpret_cast<const ushort4*>(a16 + v0 + 320);
    }

    #pragma unroll
    for (int c = 0; c < 2; ++c) {
      #pragma unroll
      for (int ks = 0; ks < 2; ++ks) {
        int vbyte = ks * 64 + ((lane >> 4) << 4);
        f16x8 pa[2];
        #pragma unroll
        for (int i2 = 0; i2 < 2; ++i2) {
          int arow = i2 * 16 + (lane & 15);
          pa[i2] = *reinterpret_cast<const f16x8*>(
              (char*)&sP[cur + c][0] + ((arow * 128 + vbyte) ^ ((arow & 7) << 4)));
        }
        #pragma unroll
        for (int n = 0; n < 2; ++n) {
          int hrow = w * 32 + n * 16 + (lane & 15);
          f16x8 vb = *reinterpret_cast<const f16x8*>(
              Vb + (size_t)hrow * LV + v0 + c * 64 + ks * 32 + ((lane >> 4) << 3));
          #pragma unroll
          for (int i2 = 0; i2 < 2; ++i2)
            acc[i2][n] = __builtin_amdgcn_mfma_f32_16x16x32_f16(pa[i2], vb, acc[i2][n], 0, 0, 0);
        }
      }
    }
    // LDS-only barrier: own ds ops done, then sync. Global loads/stores
    // (attn writes, P16 prefetch) intentionally stay in flight (no vmcnt).
    asm volatile("s_waitcnt lgkmcnt(0)" ::: "memory");
    __builtin_amdgcn_s_barrier();
  }
#undef PRODUCE

  float* Cb = C + ((size_t)b * LQ + qs * 32) * NH + w * 32;
  int rb = (lane >> 4) << 2, c0 = lane & 15;
  #pragma unroll
  for (int i2 = 0; i2 < 2; ++i2)
    #pragma unroll
    for (int j = 0; j < 4; ++j)
      #pragma unroll
      for (int n = 0; n < 2; ++n)
        Cb[(size_t)(i2 * 16 + rb + j) * NH + n * 16 + c0] = acc[i2][n][j];
}

// ============================ FALLBACK PATH (round-0) ======================

__global__ __launch_bounds__(256) void k_scores_fb(
    const float* __restrict__ Q, const float* __restrict__ V,
    float* __restrict__ S) {
  int id = blockIdx.x;
  int b = id & 7;
  int inner = id >> 3;
  int qt = inner & 31;
  int vt = inner >> 5;
  __shared__ ushort sQh[64 * 64], sQl[64 * 64], sVh[64 * 64], sVl[64 * 64];
  const float* Qb = Q + (size_t)(b * LQ + qt * 64) * NH;
  const float* Vb = V + (size_t)(b * LV + vt * 64) * NH;
  const int t = threadIdx.x;
  const int lane = t & 63;
  const int w = t >> 6;
  f32x4 acc[4] = {};
  const int row0 = t >> 4;
  const int col4 = (t & 15) << 2;
  for (int kc = 0; kc < 4; ++kc) {
    #pragma unroll
    for (int it = 0; it < 4; ++it) {
      int row = row0 + (it << 4);
      const float4 qx = *reinterpret_cast<const float4*>(Qb + (size_t)row * NH + kc * 64 + col4);
      const float4 vx = *reinterpret_cast<const float4*>(Vb + (size_t)row * NH + kc * 64 + col4);
      int off = ((row * 128 + col4 * 2) ^ ((row & 7) << 4)) >> 1;
      ushort4 h, l;
      h.x = f32_bf16(qx.x); l.x = f32_bf16(qx.x - bf16_f32(h.x));
      h.y = f32_bf16(qx.y); l.y = f32_bf16(qx.y - bf16_f32(h.y));
      h.z = f32_bf16(qx.z); l.z = f32_bf16(qx.z - bf16_f32(h.z));
      h.w = f32_bf16(qx.w); l.w = f32_bf16(qx.w - bf16_f32(h.w));
      *reinterpret_cast<ushort4*>(&sQh[off]) = h;
      *reinterpret_cast<ushort4*>(&sQl[off]) = l;
      h.x = f32_bf16(vx.x); l.x = f32_bf16(vx.x - bf16_f32(h.x));
      h.y = f32_bf16(vx.y); l.y = f32_bf16(vx.y - bf16_f32(h.y));
      h.z = f32_bf16(vx.z); l.z = f32_bf16(vx.z - bf16_f32(h.z));
      h.w = f32_bf16(vx.w); l.w = f32_bf16(vx.w - bf16_f32(h.w));
      *reinterpret_cast<ushort4*>(&sVh[off]) = h;
      *reinterpret_cast<ushort4*>(&sVl[off]) = l;
    }
    __syncthreads();
    int arow = (w << 4) + (lane & 15);
    int abase = arow * 128;
    int aswz = (arow & 7) << 4;
    #pragma unroll
    for (int ks = 0; ks < 2; ++ks) {
      int koffB = (ks << 6) + ((lane >> 4) << 4);
      int aoff = ((abase + koffB) ^ aswz) >> 1;
      bf16x8 ah = *reinterpret_cast<const bf16x8*>(&sQh[aoff]);
      bf16x8 al = *reinterpret_cast<const bf16x8*>(&sQl[aoff]);
      #pragma unroll
      for (int n = 0; n < 4; ++n) {
        int brow = (n << 4) + (lane & 15);
        int boff = (((brow * 128) + koffB) ^ ((brow & 7) << 4)) >> 1;
        bf16x8 bh = *reinterpret_cast<const bf16x8*>(&sVh[boff]);
        bf16x8 bl = *reinterpret_cast<const bf16x8*>(&sVl[boff]);
        acc[n] = __builtin_amdgcn_mfma_f32_16x16x32_bf16(ah, bh, acc[n], 0, 0, 0);
        acc[n] = __builtin_amdgcn_mfma_f32_16x16x32_bf16(ah, bl, acc[n], 0, 0, 0);
        acc[n] = __builtin_amdgcn_mfma_f32_16x16x32_bf16(al, bh, acc[n], 0, 0, 0);
      }
    }
    __syncthreads();
  }
  float* Sp = S + (size_t)b * LQ * LV + (size_t)(qt * 64) * LV + vt * 64;
  int rbase = (w << 4) + ((lane >> 4) << 2);
  int c0 = lane & 15;
  #pragma unroll
  for (int n = 0; n < 4; ++n)
    #pragma unroll
    for (int j = 0; j < 4; ++j)
      Sp[(size_t)(rbase + j) * LV + (n << 4) + c0] = acc[n][j];
}

__global__ __launch_bounds__(256) void k_stats_fb(const float* __restrict__ S,
                                                  float* __restrict__ ml) {
  const size_t r = blockIdx.x;
  const float* row = S + r * LV;
  int t = threadIdx.x;
  float4 a = *reinterpret_cast<const float4*>(row + (t << 2));
  float4 c = *reinterpret_cast<const float4*>(row + 1024 + (t << 2));
  float m = fmaxf(fmaxf(fmaxf(a.x, a.y), fmaxf(a.z, a.w)),
                  fmaxf(fmaxf(c.x, c.y), fmaxf(c.z, c.w)));
  #pragma unroll
  for (int off = 32; off; off >>= 1) m = fmaxf(m, __shfl_xor(m, off));
  __shared__ float redm[4];
  __shared__ float reds[4];
  if ((t & 63) == 0) redm[t >> 6] = m;
  __syncthreads();
  m = fmaxf(fmaxf(redm[0], redm[1]), fmaxf(redm[2], redm[3]));
  float s = __expf(a.x - m) + __expf(a.y - m) + __expf(a.z - m) + __expf(a.w - m)
          + __expf(c.x - m) + __expf(c.y - m) + __expf(c.z - m) + __expf(c.w - m);
  #pragma unroll
  for (int off = 32; off; off >>= 1) s += __shfl_xor(s, off);
  if ((t & 63) == 0) reds[t >> 6] = s;
  __syncthreads();
  if (t == 0) {
    float tot = reds[0] + reds[1] + reds[2] + reds[3];
    ml[2 * r] = m;
    ml[2 * r + 1] = 1.0f / tot;
  }
}

__global__ __launch_bounds__(256) void k_ctx_fb(
    const float* __restrict__ V, const float* __restrict__ ml,
    float* __restrict__ A, float* __restrict__ C) {
  int id = blockIdx.x;
  int b = id & 7;
  int qt = id >> 3;
  __shared__ ushort sP[32 * 40];
  __shared__ ushort sVT[256 * 40];
  __shared__ float lmv[32], liv[32];
  int t = threadIdx.x;
  int lane = t & 63;
  int w = t >> 6;
  int wr = w >> 1, wh = w & 1;
  if (t < 32) {
    size_t r = (size_t)b * LQ + qt * 32 + t;
    lmv[t] = ml[2 * r];
    liv[t] = ml[2 * r + 1];
  }
  __syncthreads();
  f32x4 acc[8] = {};
  float* Ab = A + (size_t)b * LQ * LV + (size_t)(qt * 32) * LV;
  const float* Vb = V + (size_t)b * LV * NH;
  const int prow = t >> 3;
  const int pv4 = (t & 7) << 2;
  for (int v0 = 0; v0 < LV; v0 += 32) {
    {
      float* addr = Ab + (size_t)prow * LV + v0 + pv4;
      float4 s4 = *reinterpret_cast<const float4*>(addr);
      float m = lmv[prow], inv = liv[prow];
      float4 p4;
      p4.x = __expf(s4.x - m) * inv;
      p4.y = __expf(s4.y - m) * inv;
      p4.z = __expf(s4.z - m) * inv;
      p4.w = __expf(s4.w - m) * inv;
      *reinterpret_cast<float4*>(addr) = p4;
      ushort4 pb;
      pb.x = f32_bf16(p4.x); pb.y = f32_bf16(p4.y);
      pb.z = f32_bf16(p4.z); pb.w = f32_bf16(p4.w);
      *reinterpret_cast<ushort4*>(&sP[prow * 40 + pv4]) = pb;
    }
    #pragma unroll 4
    for (int vl = 0; vl < 32; ++vl) {
      float x = Vb[(size_t)(v0 + vl) * NH + t];
      sVT[t * 40 + vl] = f32_bf16(x);
    }
    __syncthreads();
    bf16x8 pa = *reinterpret_cast<const bf16x8*>(
        &sP[((wr << 4) + (lane & 15)) * 40 + ((lane >> 4) << 3)]);
    #pragma unroll
    for (int n = 0; n < 8; ++n) {
      int hrow = (wh << 7) + (n << 4) + (lane & 15);
      bf16x8 vb = *reinterpret_cast<const bf16x8*>(
          &sVT[hrow * 40 + ((lane >> 4) << 3)]);
      acc[n] = __builtin_amdgcn_mfma_f32_16x16x32_bf16(pa, vb, acc[n], 0, 0, 0);
    }
    __syncthreads();
  }
  float* Cb = C + ((size_t)b * LQ + qt * 32) * NH;
  int rbase = (wr << 4) + ((lane >> 4) << 2);
  int c0 = lane & 15;
  #pragma unroll
  for (int n = 0; n < 8; ++n)
    #pragma unroll
    for (int j = 0; j < 4; ++j)
      Cb[(size_t)(rbase + j) * NH + (wh << 7) + (n << 4) + c0] = acc[n][j];
}

// ===========================================================================

extern "C" void kernel_launch(void* const* d_in, const int* in_sizes, int n_in,
                              void* d_out, int out_size, void* d_ws, size_t ws_size,
                              hipStream_t stream) {
  const float* Q = (const float*)d_in[0];
  const float* V = (const float*)d_in[1];
  float* out = (float*)d_out;
  float* C = out;                                  // context: 8*2048*256
  float* A = out + (size_t)NB * LQ * NH;           // attn:    8*2048*2048

  const size_t NE = (size_t)NB * LQ * NH;          // 4,194,304 elems
  const size_t PSN = (size_t)NB * LQ * 16;         // 262,144 float2
  const size_t need = NE * 2 * 4 + PSN * 8;        // ≈ 34 MiB
  const int DYN_LDS = 2 * 3 * 256 * 64;            // 98304 B

  bool big_lds_ok =
      hipFuncSetAttribute((const void*)k_scores9,
                          hipFuncAttributeMaxDynamicSharedMemorySize,
                          DYN_LDS) == hipSuccess;

  if (ws_size >= need && big_lds_ok) {
    ushort* Qh  = (ushort*)d_ws;
    ushort* Ql  = Qh + NE;
    ushort* Vf  = Ql + NE;
    ushort* VfT = Vf + NE;
    float2* PS  = (float2*)(VfT + NE);
    k_prep2<<<dim3(4096 + NB * 32 * 4), dim3(256), 0, stream>>>(Q, V, Qh, Ql, Vf, VfT);
    k_scores9<<<dim3(NB * 8 * 8), dim3(512), DYN_LDS, stream>>>(Qh, Ql, Vf, A, PS);
    k_ctx12<<<dim3(NB * 64), dim3(512), 0, stream>>>(VfT, PS, A, C);
  } else {
    float* ml = (float*)d_ws;                      // 128 KB fallback scratch
    k_scores_fb<<<dim3(NB * 32 * 32), dim3(256), 0, stream>>>(Q, V, A);
    k_stats_fb<<<dim3(NB * LQ), dim3(256), 0, stream>>>(A, ml);
    k_ctx_fb<<<dim3(NB * 64), dim3(256), 0, stream>>>(V, ml, A, C);
  }
}